// Round 13
// baseline (488.946 us; speedup 1.0000x reference)
//
#include <hip/hip_runtime.h>
#include <math.h>
#include <stdint.h>

// AnomalyAttention: B=4, L=1024, H=8, E=64, f32 in/out.
// Outputs flat: V [B,L,H,E], series [B,H,L,L], prior [B,H,L,L], sigma4 [B,H,L,L].
//
// R9: 2-blocks/CU attempt neutral (81920B x2 = exact 160KiB pool -> 2nd block never fit;
// ~94% stall at 1 block/CU). This round:
//  - 512-thr blocks, ROWS=16, LDS 45184B -> 3 blocks/CU (24 waves), launch_bounds(512,6)
//  - QK loads K DIRECT from global (L2-hot, per-lane B-frag = 2x float4 contiguous):
//    no K staging, ZERO barriers in QK, register prefetch of next tile
//  - prior+sigma4 fused here (writes overlap PV staging latency); single kernel
// mfma_f32_16x16x32_bf16 (guide-verified): A lane l: m=l%16, k=(l/16)*8+i;
// B: n=l%16, k=(l/16)*8+i; C/D: col(n)=l&15, row(m)=(l>>4)*4+reg.

#define BB 4
#define LL 1024
#define HH 8
#define EE 64
#define ROWS 16
#define THREADS 512

typedef __attribute__((ext_vector_type(8))) short bf16x8;
typedef __attribute__((ext_vector_type(4))) float f32x4;

static constexpr size_t OFF_V      = 0;
static constexpr size_t OFF_SERIES = (size_t)BB * LL * HH * EE;                  // 2097152
static constexpr size_t OFF_PRIOR  = OFF_SERIES + (size_t)BB * HH * LL * LL;     // 35651584
static constexpr size_t OFF_SIGMA4 = OFF_PRIOR + (size_t)BB * HH * LL * LL;      // 69206016

// LDS: sS bf16[16][1024] @0 (32768) | Vt bf16[64][64] @32768 (8192) | red f32 @40960 (4096)
//      rinv f32[16] @45056 | ssig f32[16] @45120  => 45184 B -> 3 blocks/CU
static constexpr int LDS_BYTES = 45184;

__device__ __forceinline__ short f2bf(float f) {
    union { float f; uint32_t u; } v; v.f = f;
    uint32_t r = (v.u + 0x7FFFu + ((v.u >> 16) & 1u)) >> 16;   // RNE
    return (short)r;
}
__device__ __forceinline__ float bf2f(short s) {
    union { uint32_t u; float f; } v; v.u = ((uint32_t)(unsigned short)s) << 16;
    return v.f;
}

__global__ __launch_bounds__(THREADS, 6) void anomaly_fused_kernel(
    const float* __restrict__ Q, const float* __restrict__ K,
    const float* __restrict__ V, const float* __restrict__ sigma,
    float* __restrict__ out)
{
    extern __shared__ char lds[];
    short* sS   = (short*)lds;                  // [16][1024] bf16, grp8 ^ (row&7)
    short* Vt   = (short*)(lds + 32768);        // [64][64] bf16, grp8 ^ (e&7)
    float* red  = (float*)(lds + 40960);        // 4 tiles x 64 lanes x f32x4
    float* rinv = (float*)(lds + 45056);        // [16]
    float* ssig = (float*)(lds + 45120);        // [16]

    const int tid  = threadIdx.x;
    const int lane = tid & 63;
    const int w    = tid >> 6;                  // 8 waves
    const int tile = blockIdx.x & 63;           // tile fastest -> blocks share (b,h) K/V in L2
    const int bh   = blockIdx.x >> 6;
    const int b    = bh >> 3, h = bh & 7;
    const int r0   = tile * ROWS;
    const int ntiles = (r0 >> 4) + 1;           // 16-col QK tiles
    const int NC     = r0 + 16;                 // computed cols (exact)
    const int NCpad  = (NC + 63) & ~63;         // PV works in 64-j chunks
    const int NVC    = NCpad >> 6;

    const float* Kbase = K + (size_t)b * (LL * HH * EE) + h * EE;   // row j at +j*512
    const float* Vbase = V + (size_t)b * (LL * HH * EE) + h * EE;

    // ---- zero-fill sS tail cols [NC, NCpad) so PV can run full 64-j chunks ----
    for (int x = tid; x < (NCpad - NC) * ROWS; x += THREADS) {
        int r_ = x & 15;
        int c  = NC + (x >> 4);
        sS[r_ * 1024 + (((c >> 3) ^ (r_ & 7)) << 3) + (c & 7)] = 0;
    }

    // ---- Q A-fragment in registers (all waves: same 16 rows) ----
    bf16x8 qf0, qf1;
    {
        int qrow = r0 + (lane & 15);
        const float* qp = Q + ((size_t)(b * LL + qrow) * HH + h) * EE + ((lane >> 4) << 3);
        float4 a = *(const float4*)qp;
        float4 c = *(const float4*)(qp + 4);
        qf0[0]=f2bf(a.x); qf0[1]=f2bf(a.y); qf0[2]=f2bf(a.z); qf0[3]=f2bf(a.w);
        qf0[4]=f2bf(c.x); qf0[5]=f2bf(c.y); qf0[6]=f2bf(c.z); qf0[7]=f2bf(c.w);
        float4 a2 = *(const float4*)(qp + 32);
        float4 c2 = *(const float4*)(qp + 36);
        qf1[0]=f2bf(a2.x); qf1[1]=f2bf(a2.y); qf1[2]=f2bf(a2.z); qf1[3]=f2bf(a2.w);
        qf1[4]=f2bf(c2.x); qf1[5]=f2bf(c2.y); qf1[6]=f2bf(c2.z); qf1[7]=f2bf(c2.w);
    }

    // ---- QK: per-wave independent 16-col tiles, K direct from global, reg prefetch ----
    {
        const int jro = lane & 15;              // lane's B-column = K row offset
        const int eo  = (lane >> 4) << 3;       // e-group base (0,8,16,24)
        float4 ka, kb, kc, kd;
        int jt = w;
        if (jt < ntiles) {
            const float* kp = Kbase + (size_t)(jt * 16 + jro) * 512 + eo;
            ka = *(const float4*)kp;       kb = *(const float4*)(kp + 4);
            kc = *(const float4*)(kp + 32); kd = *(const float4*)(kp + 36);
        }
        for (; jt < ntiles; jt += 8) {
            float4 c0 = ka, c1 = kb, c2 = kc, c3 = kd;
            if (jt + 8 < ntiles) {              // prefetch next tile (hidden under mfma+exp)
                const float* kp = Kbase + (size_t)((jt + 8) * 16 + jro) * 512 + eo;
                ka = *(const float4*)kp;       kb = *(const float4*)(kp + 4);
                kc = *(const float4*)(kp + 32); kd = *(const float4*)(kp + 36);
            }
            bf16x8 b0, b1;
            b0[0]=f2bf(c0.x); b0[1]=f2bf(c0.y); b0[2]=f2bf(c0.z); b0[3]=f2bf(c0.w);
            b0[4]=f2bf(c1.x); b0[5]=f2bf(c1.y); b0[6]=f2bf(c1.z); b0[7]=f2bf(c1.w);
            b1[0]=f2bf(c2.x); b1[1]=f2bf(c2.y); b1[2]=f2bf(c2.z); b1[3]=f2bf(c2.w);
            b1[4]=f2bf(c3.x); b1[5]=f2bf(c3.y); b1[6]=f2bf(c3.z); b1[7]=f2bf(c3.w);
            f32x4 acc = {0.f, 0.f, 0.f, 0.f};
            acc = __builtin_amdgcn_mfma_f32_16x16x32_bf16(qf0, b0, acc, 0, 0, 0);
            acc = __builtin_amdgcn_mfma_f32_16x16x32_bf16(qf1, b1, acc, 0, 0, 0);
            // mask + exp (no-max softmax: safe) + bf16 store to sS
            int col = jt * 16 + jro;
            int gc = col >> 3, co = col & 7;
#pragma unroll
            for (int q = 0; q < 4; ++q) {
                int rt = ((lane >> 4) << 2) + q;
                float e = (col <= r0 + rt) ? __expf(acc[q] * 0.125f) : 0.f;
                sS[rt * 1024 + ((gc ^ (rt & 7)) << 3) + co] = f2bf(e);
            }
        }
    }
    __syncthreads();                            // sS (incl. zero tail) complete

    // ---- V chunk-0 prefetch: latency hides under rowsum + series + prior ----
    const int vj  = tid >> 3;                   // 0..63
    const int ve8 = (tid & 7) * 8;              // e-group of 8
    float4 vp0 = *(const float4*)&Vbase[(size_t)vj * 512 + ve8];
    float4 vp1 = *(const float4*)&Vbase[(size_t)vj * 512 + ve8 + 4];

    // ---- rowsum -> rinv; sigma chain once per row -> ssig ----
    {
        int r = tid >> 5, j2 = tid & 31;
        float sum = 0.f;
        for (int g = j2; g < (NCpad >> 3); g += 32) {
            bf16x8 v = *(const bf16x8*)&sS[r * 1024 + ((g ^ (r & 7)) << 3)];
            float s0 = bf2f(v[0]) + bf2f(v[1]), s1 = bf2f(v[2]) + bf2f(v[3]);
            float s2 = bf2f(v[4]) + bf2f(v[5]), s3 = bf2f(v[6]) + bf2f(v[7]);
            sum += (s0 + s1) + (s2 + s3);
        }
        sum += __shfl_xor(sum, 1);
        sum += __shfl_xor(sum, 2);
        sum += __shfl_xor(sum, 4);
        sum += __shfl_xor(sum, 8);
        sum += __shfl_xor(sum, 16);
        if (j2 == 0) rinv[r] = 1.0f / sum;
        if (j2 == 1) {                          // sigma chain, one thread per row
            float x  = sigma[((size_t)b * LL + r0 + r) * HH + h];
            float sg = 1.0f / (1.0f + __expf(-5.0f * x)) + 1e-5f;
            ssig[r]  = __expf(1.0986122886681098f * sg) - 1.0f;   // 3^sg - 1
        }
    }
    __syncthreads();

    const int gc128 = tid & 127;                // 8-col group 0..127
    const int rb    = tid >> 7;                 // 0..3

    // ---- series write: coalesced f32 (2KB/wave-instr) ----
    {
        size_t base = OFF_SERIES + ((size_t)bh * LL + r0) * LL;
#pragma unroll
        for (int it = 0; it < 4; ++it) {
            int r_ = rb + it * 4;
            float4 o0, o1;
            if (gc128 * 8 < NC) {
                float ri = rinv[r_];
                bf16x8 v = *(const bf16x8*)&sS[r_ * 1024 + ((gc128 ^ (r_ & 7)) << 3)];
                o0 = make_float4(bf2f(v[0])*ri, bf2f(v[1])*ri, bf2f(v[2])*ri, bf2f(v[3])*ri);
                o1 = make_float4(bf2f(v[4])*ri, bf2f(v[5])*ri, bf2f(v[6])*ri, bf2f(v[7])*ri);
            } else {
                o0 = make_float4(0.f, 0.f, 0.f, 0.f); o1 = o0;  // poisoned buffer: masked = 0
            }
            *(float4*)(out + base + (size_t)r_ * LL + gc128 * 8)     = o0;
            *(float4*)(out + base + (size_t)r_ * LL + gc128 * 8 + 4) = o1;
        }
    }

    // ---- prior + sigma4 (fused; overlaps V prefetch / PV stalls) ----
    {
        size_t pbase = (size_t)bh * LL + r0;
#pragma unroll
        for (int it = 0; it < 4; ++it) {
            int r_ = rb + it * 4;
            int i  = r0 + r_;
            float s      = ssig[r_];
            float inv2s2 = 0.5f / (s * s);
            float coef   = 0.3989422804014327f / s;
            int j0 = gc128 * 8;
            float4 p0, p1;
            {
                float d0 = (float)(i - (j0 + 0)), d1 = (float)(i - (j0 + 1));
                float d2 = (float)(i - (j0 + 2)), d3 = (float)(i - (j0 + 3));
                p0 = make_float4(coef * __expf(-d0*d0*inv2s2), coef * __expf(-d1*d1*inv2s2),
                                 coef * __expf(-d2*d2*inv2s2), coef * __expf(-d3*d3*inv2s2));
                float d4 = (float)(i - (j0 + 4)), d5 = (float)(i - (j0 + 5));
                float d6 = (float)(i - (j0 + 6)), d7 = (float)(i - (j0 + 7));
                p1 = make_float4(coef * __expf(-d4*d4*inv2s2), coef * __expf(-d5*d5*inv2s2),
                                 coef * __expf(-d6*d6*inv2s2), coef * __expf(-d7*d7*inv2s2));
            }
            size_t rowb = (pbase + r_) * LL + j0;
            *(float4*)(out + OFF_PRIOR + rowb)      = p0;
            *(float4*)(out + OFF_PRIOR + rowb + 4)  = p1;
            *(float4*)(out + OFF_SIGMA4 + rowb)     = make_float4(s, s, s, s);
            *(float4*)(out + OFF_SIGMA4 + rowb + 4) = make_float4(s, s, s, s);
        }
    }

    // ---- PV: 64-j chunks; 8 waves = kh(2) x eg(4); Vt[e][j] bf16 swizzled ----
    const int eg = w & 3;
    const int kh = w >> 2;
    f32x4 pacc = {0.f, 0.f, 0.f, 0.f};

    for (int vc = 0; vc < NVC; ++vc) {
        __syncthreads();                        // prev chunk MFMA reads done -> Vt writable
        {
            float vv[8] = {vp0.x, vp0.y, vp0.z, vp0.w, vp1.x, vp1.y, vp1.z, vp1.w};
            int jg = vj >> 3, jo = vj & 7;
#pragma unroll
            for (int i = 0; i < 8; ++i) {
                int e = ve8 + i;
                Vt[e * 64 + ((jg ^ (e & 7)) << 3) + jo] = f2bf(vv[i]);
            }
        }
        if (vc + 1 < NVC) {
            vp0 = *(const float4*)&Vbase[(size_t)((vc + 1) * 64 + vj) * 512 + ve8];
            vp1 = *(const float4*)&Vbase[(size_t)((vc + 1) * 64 + vj) * 512 + ve8 + 4];
        }
        __syncthreads();                        // Vt visible

        {
            int rt = lane & 15;                 // A m-row
            int gg = vc * 8 + kh * 4 + (lane >> 4);
            bf16x8 af = *(const bf16x8*)&sS[rt * 1024 + ((gg ^ (rt & 7)) << 3)];
            int e  = eg * 16 + (lane & 15);     // B n-col
            int jg = kh * 4 + (lane >> 4);
            bf16x8 bf = *(const bf16x8*)&Vt[e * 64 + ((jg ^ (e & 7)) << 3)];
            pacc = __builtin_amdgcn_mfma_f32_16x16x32_bf16(af, bf, pacc, 0, 0, 0);
        }
    }

    // ---- kh reduce + scaled V write ----
    __syncthreads();                            // PV reads done; Vt dead
    if (kh == 0) *(f32x4*)&red[(eg * 64 + lane) * 4] = pacc;
    __syncthreads();
    if (kh == 1) {
        f32x4 o = *(const f32x4*)&red[(eg * 64 + lane) * 4];
#pragma unroll
        for (int q = 0; q < 4; ++q) {
            int rt = ((lane >> 4) << 2) + q;
            out[OFF_V + ((size_t)(b * LL + r0 + rt) * HH + h) * EE + eg * 16 + (lane & 15)]
                = (pacc[q] + o[q]) * rinv[rt];
        }
    }
}

extern "C" void kernel_launch(void* const* d_in, const int* in_sizes, int n_in,
                              void* d_out, int out_size, void* d_ws, size_t ws_size,
                              hipStream_t stream) {
    const float* Q     = (const float*)d_in[0];
    const float* K     = (const float*)d_in[1];
    const float* V     = (const float*)d_in[2];
    const float* sigma = (const float*)d_in[3];
    float* out = (float*)d_out;

    anomaly_fused_kernel<<<dim3(BB * HH * (LL / ROWS)), dim3(THREADS), LDS_BYTES, stream>>>(
        Q, K, V, sigma, out);
}